// Round 10
// baseline (164.835 us; speedup 1.0000x reference)
//
#include <hip/hip_runtime.h>

typedef __bf16 bf16_t;
typedef bf16_t bf16x8 __attribute__((ext_vector_type(8)));
typedef float f32x4 __attribute__((ext_vector_type(4)));

#define NB 8
#define TT 2048
#define DIN 1024
#define HH 64
#define MM (NB * TT)

__device__ __forceinline__ unsigned short f2bf(float f) {
    unsigned int u = __float_as_uint(f);
    u += 0x7fffu + ((u >> 16) & 1u);   // round-to-nearest-even
    return (unsigned short)(u >> 16);
}
__device__ __forceinline__ float bf2f(unsigned short h) {
    return __uint_as_float((unsigned int)h << 16);
}

// async global->LDS, 16B per lane. LDS dest = base + lane*16 (linear);
// global src may be per-lane (16B-aligned). Exec-masked.
__device__ __forceinline__ void async16(void* l, const void* g) {
    __builtin_amdgcn_global_load_lds(
        (const __attribute__((address_space(1))) unsigned int*)g,
        (__attribute__((address_space(3))) unsigned int*)l, 16, 0, 0);
}

// Per-block dtype probe: low-bf16 exponent field of x words.
// fp32 data -> ~20% in range; bf16 -> ~100%. Returns 1 if fp32.
__device__ __forceinline__ int block_detect_f32(const unsigned int* __restrict__ xw,
                                                int tid, int* sflag) {
    if (tid < 64) {
        unsigned int u = xw[tid];
        unsigned int e = (u >> 7) & 0xFFu;
        unsigned long long m = __ballot(e >= 100u && e <= 150u);
        if (tid == 0) *sflag = (__popcll(m) < 48) ? 1 : 0;
    }
    __syncthreads();
    return *sflag;
}

// ------------------------------------------------------------------
// LDS-tiled W transpose: Wt[w*64+n][k] = W_w[k][n], bf16.
// ------------------------------------------------------------------
__global__ __launch_bounds__(256) void transpose_w_kernel(
    const void* __restrict__ Wq, const void* __restrict__ Wk,
    const void* __restrict__ Wv, const unsigned int* __restrict__ xw,
    unsigned short* __restrict__ Wt) {
    __shared__ int sflag;
    __shared__ unsigned short ts[64][68];
    const int tid = threadIdx.x;
    const int isf32 = block_detect_f32(xw, tid, &sflag);
    const int w = blockIdx.x >> 4, kt = blockIdx.x & 15;
    const void* W = (w == 0) ? Wq : (w == 1) ? Wk : Wv;
    const int kk = tid >> 4, nn = (tid & 15) * 4;
#pragma unroll
    for (int j = 0; j < 4; ++j) {
        int k = kk + j * 16;
        if (isf32) {
            float4 f = *(const float4*)((const float*)W + (size_t)(kt * 64 + k) * 64 + nn);
            ts[k][nn + 0] = f2bf(f.x); ts[k][nn + 1] = f2bf(f.y);
            ts[k][nn + 2] = f2bf(f.z); ts[k][nn + 3] = f2bf(f.w);
        } else {
            *(uint2*)&ts[k][nn] =
                *(const uint2*)((const unsigned short*)W + (size_t)(kt * 64 + k) * 64 + nn);
        }
    }
    __syncthreads();
    const int n = tid >> 2, k0 = (tid & 3) * 16;
    unsigned short tmp[16];
#pragma unroll
    for (int j = 0; j < 16; ++j) tmp[j] = ts[k0 + j][n];
    unsigned short* dst = Wt + (size_t)(w * 64 + n) * 1024 + kt * 64 + k0;
    *(uint4*)(dst + 0) = *(uint4*)&tmp[0];
    *(uint4*)(dst + 8) = *(uint4*)&tmp[8];
}

// ------------------------------------------------------------------
// Fused QKV projection v6 (unchanged from R9 — verified < 40 us).
// ------------------------------------------------------------------
#define XR 72      /* x LDS row stride in bf16 elems (144 B) */
#define WROWC 9    /* W LDS row = 9 chunks = 144 B (128 payload) */

__global__ __launch_bounds__(256, 2) void proj_kernel(
    const void* __restrict__ xraw, const unsigned short* __restrict__ Wt,
    unsigned short* __restrict__ qbuf, unsigned short* __restrict__ kbuf,
    unsigned short* __restrict__ vtbuf) {
    __shared__ int sflag;
    __shared__ __align__(16) unsigned short xs[64 * XR];            // 9216 B
    __shared__ __align__(16) unsigned char wlds[96 * WROWC * 16];   // 13824 B

    const int tid = threadIdx.x;
    const int isf32 = block_detect_f32((const unsigned int*)xraw, tid, &sflag);
    const int m0 = blockIdx.x * 64;
    const int nh = blockIdx.y;
    const int wave = tid >> 6, lane = tid & 63, quad = lane >> 4, l15 = lane & 15;
    const int rw = wave & 1, cw = wave >> 1;

    const float* xf = (const float*)xraw;
    const unsigned short* xb = (const unsigned short*)xraw;
    const unsigned char* wg = (const unsigned char*)Wt;

    const unsigned char* wsrc[4];
    unsigned int wdst[4];
    int nw = 0;
#pragma unroll
    for (int j = 0; j < 4; ++j) {
        int c = (wave + 4 * j) * 64 + lane;
        if (c < 864) {
            int R = c / WROWC, cc = c % WROWC;
            int ccu = (cc > 7) ? 0 : cc;
            wsrc[nw] = wg + (size_t)(nh * 96 + R) * 2048 + ccu * 16;
            wdst[nw] = c * 16;
            ++nw;
        }
    }

    const int xr = tid >> 2, xc = (tid & 3) * 16;
    float4 px[4];
    uint4  pxb[2];
    auto ldx = [&](int k0) {
        if (isf32) {
            const float* g = xf + (size_t)(m0 + xr) * DIN + k0 + xc;
#pragma unroll
            for (int j = 0; j < 4; ++j) px[j] = *(const float4*)(g + j * 4);
        } else {
            const unsigned short* g = xb + (size_t)(m0 + xr) * DIN + k0 + xc;
            pxb[0] = *(const uint4*)(g + 0);
            pxb[1] = *(const uint4*)(g + 8);
        }
    };

    f32x4 acc[2][3];
#pragma unroll
    for (int rt = 0; rt < 2; ++rt)
#pragma unroll
        for (int ct = 0; ct < 3; ++ct)
            acc[rt][ct] = (f32x4){0.f, 0.f, 0.f, 0.f};

    ldx(0);
    size_t woff = 0;
    for (int it = 0; it < 16; ++it) {
        __syncthreads();
        if (isf32) {
            unsigned short t[16];
#pragma unroll
            for (int j = 0; j < 4; ++j) {
                t[j * 4 + 0] = f2bf(px[j].x); t[j * 4 + 1] = f2bf(px[j].y);
                t[j * 4 + 2] = f2bf(px[j].z); t[j * 4 + 3] = f2bf(px[j].w);
            }
            *(uint4*)&xs[xr * XR + xc + 0] = *(uint4*)&t[0];
            *(uint4*)&xs[xr * XR + xc + 8] = *(uint4*)&t[8];
        } else {
            *(uint4*)&xs[xr * XR + xc + 0] = pxb[0];
            *(uint4*)&xs[xr * XR + xc + 8] = pxb[1];
        }
        for (int j = 0; j < nw; ++j) async16(&wlds[wdst[j]], wsrc[j] + woff);
        woff += 128;
        __syncthreads();

        if (it < 15) ldx((it + 1) * 64);

#pragma unroll
        for (int ks = 0; ks < 2; ++ks) {
            bf16x8 a[2], b[3];
#pragma unroll
            for (int rt = 0; rt < 2; ++rt)
                a[rt] = *(const bf16x8*)
                    &xs[(rw * 32 + rt * 16 + l15) * XR + ks * 32 + quad * 8];
#pragma unroll
            for (int ct = 0; ct < 3; ++ct)
                b[ct] = *(const bf16x8*)
                    &wlds[(cw * 48 + ct * 16 + l15) * (WROWC * 16) + ks * 64 + quad * 16];
#pragma unroll
            for (int rt = 0; rt < 2; ++rt)
#pragma unroll
                for (int ct = 0; ct < 3; ++ct)
                    acc[rt][ct] = __builtin_amdgcn_mfma_f32_16x16x32_bf16(
                        a[rt], b[ct], acc[rt][ct], 0, 0, 0);
        }
    }

#pragma unroll
    for (int rt = 0; rt < 2; ++rt)
#pragma unroll
        for (int ct = 0; ct < 3; ++ct) {
            int n = nh * 96 + cw * 48 + ct * 16 + l15;
            int wsel = n >> 6, nn = n & 63;
#pragma unroll
            for (int reg = 0; reg < 4; ++reg) {
                int m = m0 + rw * 32 + rt * 16 + quad * 4 + reg;
                unsigned short bv = f2bf(acc[rt][ct][reg]);
                if (wsel == 0)      qbuf[(size_t)m * HH + nn] = bv;
                else if (wsel == 1) kbuf[(size_t)m * HH + nn] = bv;
                else {
                    int bb = m >> 11, t = m & 2047;
                    vtbuf[((size_t)bb * HH + nn) * TT + t] = bv;
                }
            }
        }
}

// ------------------------------------------------------------------
// Split-column flash attention v3: async16 DOUBLE-BUFFERED K/V tiles,
// 1 barrier/iter (DMA for tile i+1 overlaps full compute of tile i).
// Q-fragments hoisted to registers (direct global load, no Qr LDS).
// O_part written bf16. grid (80, 8).
// ------------------------------------------------------------------
#define KROWC 9    /* K/V LDS row = 9 chunks = 144 B (128 payload) */

__global__ __launch_bounds__(256) void attn_kernel(
    const unsigned short* __restrict__ rowbuf,  // k-proj [b][t][h]
    const unsigned short* __restrict__ colbuf,  // q-proj [b][s][h]
    const unsigned short* __restrict__ vtbuf,   // [b][h][s]
    unsigned short* __restrict__ O_part,        // [slot][64][64] bf16
    float* __restrict__ l_part) {               // [slot][64]

    __shared__ __align__(16) unsigned char klds[2][64 * KROWC * 16];  // 2x9216
    __shared__ __align__(16) unsigned char vlds[2][64 * KROWC * 16];  // 2x9216
    __shared__ __align__(16) unsigned short P_s[4][16][72];           // 9216

    const int tid  = threadIdx.x;
    const int bx   = blockIdx.x;   // 0..79
    const int b    = blockIdx.y;
    int rt, ch;
    if (bx < 8)       { rt = bx;                 ch = 0; }
    else if (bx < 24) { rt = 8 + ((bx - 8) >> 1);  ch = (bx - 8) & 1; }
    else if (bx < 48) { rt = 16 + (bx - 24) / 3;   ch = (bx - 24) % 3; }
    else              { rt = 24 + ((bx - 48) >> 2); ch = (bx - 48) & 3; }
    const int nct = min(8, rt + 1 - ch * 8);
    const int t0 = rt * 64;
    const int slot = b * 80 + bx;

    const int wave = tid >> 6, lane = tid & 63, quad = lane >> 4, l15 = lane & 15;

    // --- staging address precompute (K: 576 chunks = 9 wave-insts; V same) ---
    const unsigned char* kg = (const unsigned char*)colbuf;   // score cols = q-proj
    const unsigned char* vg = (const unsigned char*)vtbuf;
    const int s0base = ch * 8 * 64;
    const unsigned char* ksrc[3]; unsigned int kdst[3]; int nk = 0;
    const unsigned char* vsrc[3]; unsigned int vdst[3]; int nv = 0;
#pragma unroll
    for (int j = 0; j < 3; ++j) {
        int inst = wave + 4 * j;
        if (inst < 9) {
            int c = inst * 64 + lane;
            int R = c / KROWC, cc = c % KROWC;
            int ccu = (cc > 7) ? 0 : cc;
            ksrc[nk] = kg + ((size_t)(b * TT + s0base + R)) * 128 + ccu * 16;
            kdst[nk] = c * 16;
            ++nk;
            vsrc[nv] = vg + ((size_t)(b * 64 + R) * TT + s0base) * 2 + ccu * 16;
            vdst[nv] = c * 16;
            ++nv;
        }
    }

    auto stage = [&](int buf, size_t koff, size_t voff) {
        for (int j = 0; j < nk; ++j) async16(&klds[buf][kdst[j]], ksrc[j] + koff);
        for (int j = 0; j < nv; ++j) async16(&vlds[buf][vdst[j]], vsrc[j] + voff);
    };

    // Q fragments direct from global (per-lane 16B aligned loads)
    bf16x8 aq[2];
#pragma unroll
    for (int ks = 0; ks < 2; ++ks)
        aq[ks] = *(const bf16x8*)
            &rowbuf[((size_t)b * TT + t0 + wave * 16 + l15) * HH + ks * 32 + quad * 8];

    f32x4 o[4];
#pragma unroll
    for (int c = 0; c < 4; ++c) o[c] = (f32x4){0.f, 0.f, 0.f, 0.f};
    float ls[4] = {0.f, 0.f, 0.f, 0.f};

    const float SCL2 = 0.125f * 1.4426950408889634f;  // H^-0.5 * log2(e)

    stage(0, 0, 0);
    __syncthreads();   // buf0 DMA drained

    for (int i = 0; i < nct; ++i) {
        const int stc = ch * 8 + i;
        const int s0 = stc * 64;
        const int cur = i & 1;
        if (i + 1 < nct) stage(cur ^ 1, (size_t)(i + 1) * 64 * 128, (size_t)(i + 1) * 128);

        // S = Qr * Kc^T
        f32x4 scf[4];
#pragma unroll
        for (int c = 0; c < 4; ++c) scf[c] = (f32x4){0.f, 0.f, 0.f, 0.f};
#pragma unroll
        for (int ks = 0; ks < 2; ++ks) {
#pragma unroll
            for (int c = 0; c < 4; ++c) {
                bf16x8 bb = *(const bf16x8*)
                    &klds[cur][(c * 16 + l15) * (KROWC * 16) + ks * 64 + quad * 16];
                scf[c] = __builtin_amdgcn_mfma_f32_16x16x32_bf16(aq[ks], bb, scf[c], 0, 0, 0);
            }
        }

        const bool diag = (stc == rt);
#pragma unroll
        for (int r = 0; r < 4; ++r) {
            const int tg = t0 + wave * 16 + quad * 4 + r;
#pragma unroll
            for (int c = 0; c < 4; ++c) {
                float arg = fmaf(scf[c][r], SCL2, -30.f);
                if (diag && (s0 + c * 16 + l15) > tg) arg = -200.f;
                float p = __builtin_amdgcn_exp2f(arg);
                P_s[wave][quad * 4 + r][c * 16 + l15] = f2bf(p);
                ls[r] += p;
            }
        }
        // P_s per-wave: intra-wave LDS RAW, lgkmcnt suffices.
#pragma unroll
        for (int ks = 0; ks < 2; ++ks) {
            bf16x8 ap = *(const bf16x8*)&P_s[wave][l15][ks * 32 + quad * 8];
#pragma unroll
            for (int c = 0; c < 4; ++c) {
                bf16x8 bv = *(const bf16x8*)
                    &vlds[cur][(c * 16 + l15) * (KROWC * 16) + ks * 64 + quad * 16];
                o[c] = __builtin_amdgcn_mfma_f32_16x16x32_bf16(ap, bv, o[c], 0, 0, 0);
            }
        }
        __syncthreads();   // cur consumed by all waves; next-buf DMA drained
    }

    // per-row l: reduce over the 16 l15 lanes
#pragma unroll
    for (int r = 0; r < 4; ++r) {
#pragma unroll
        for (int off = 1; off < 16; off <<= 1) ls[r] += __shfl_xor(ls[r], off);
    }
    if (l15 == 0) {
#pragma unroll
        for (int r = 0; r < 4; ++r)
            l_part[(size_t)slot * 64 + wave * 16 + quad * 4 + r] = ls[r];
    }
#pragma unroll
    for (int c = 0; c < 4; ++c)
#pragma unroll
        for (int r = 0; r < 4; ++r)
            O_part[(size_t)slot * 4096 + (wave * 16 + quad * 4 + r) * 64 + c * 16 + l15] =
                f2bf(o[c][r]);
}

// ------------------------------------------------------------------
// Combine partials (bf16 O_part): out = (sum O)/ (sum l). grid (32,8).
// ------------------------------------------------------------------
__global__ __launch_bounds__(256) void combine_kernel(
    const unsigned short* __restrict__ O_part, const float* __restrict__ l_part,
    const unsigned int* __restrict__ xw, void* __restrict__ outraw) {
    __shared__ int sflag;
    const int tid = threadIdx.x;
    const int isf32 = block_detect_f32(xw, tid, &sflag);
    const int rt = blockIdx.x, b = blockIdx.y;
    const int nch = rt / 8 + 1;
    const int off = (rt < 8) ? rt : (rt < 16) ? 8 + 2 * (rt - 8)
                   : (rt < 24) ? 24 + 3 * (rt - 16) : 48 + 4 * (rt - 24);
    const int slot0 = b * 80 + off;

    const int row = tid >> 2, cb = (tid & 3) * 16;
    float a[16];
#pragma unroll
    for (int e = 0; e < 16; ++e) a[e] = 0.f;
    float l = 0.f;
    for (int j = 0; j < nch; ++j) {
        const unsigned short* p = O_part + (size_t)(slot0 + j) * 4096 + row * 64 + cb;
        uint4 u0 = *(const uint4*)(p + 0);
        uint4 u1 = *(const uint4*)(p + 8);
        const unsigned short* h = (const unsigned short*)&u0;
#pragma unroll
        for (int e = 0; e < 8; ++e) a[e] += bf2f(h[e]);
        h = (const unsigned short*)&u1;
#pragma unroll
        for (int e = 0; e < 8; ++e) a[8 + e] += bf2f(h[e]);
        l += l_part[(size_t)(slot0 + j) * 64 + row];
    }
    const float inv = 1.f / l;
    const size_t base = ((size_t)b * TT + rt * 64 + row) * HH + cb;
    if (isf32) {
        float* outf = (float*)outraw;
#pragma unroll
        for (int q = 0; q < 4; ++q) {
            float4 v = {a[q * 4] * inv, a[q * 4 + 1] * inv,
                        a[q * 4 + 2] * inv, a[q * 4 + 3] * inv};
            *(float4*)(outf + base + q * 4) = v;
        }
    } else {
        unsigned short hh[16];
#pragma unroll
        for (int e = 0; e < 16; ++e) hh[e] = f2bf(a[e] * inv);
        unsigned short* outb = (unsigned short*)outraw;
        *(uint4*)(outb + base + 0) = *(uint4*)&hh[0];
        *(uint4*)(outb + base + 8) = *(uint4*)&hh[8];
    }
}

extern "C" void kernel_launch(void* const* d_in, const int* in_sizes, int n_in,
                              void* d_out, int out_size, void* d_ws, size_t ws_size,
                              hipStream_t stream) {
    const void* x  = d_in[0];
    const void* Wq = d_in[1];
    const void* Wk = d_in[2];
    const void* Wv = d_in[3];
    unsigned short* ws = (unsigned short*)d_ws;

    unsigned short* qbuf  = ws;                          // 2 MB
    unsigned short* kbuf  = ws + (size_t)MM * HH;        // 2 MB
    unsigned short* vtbuf = ws + (size_t)2 * MM * HH;    // 2 MB
    unsigned short* wtbuf = ws + (size_t)3 * MM * HH;    // 384 KB
    unsigned short* O_part = wtbuf + 3 * 65536;          // 5.25 MB (bf16)
    float* l_part = (float*)(O_part + (size_t)640 * 4096);  // 164 KB

    hipLaunchKernelGGL(transpose_w_kernel, dim3(48), dim3(256), 0, stream,
                       Wq, Wk, Wv, (const unsigned int*)x, wtbuf);
    hipLaunchKernelGGL(proj_kernel, dim3(256, 2), dim3(256), 0, stream,
                       x, wtbuf, qbuf, kbuf, vtbuf);
    hipLaunchKernelGGL(attn_kernel, dim3(80, 8), dim3(256), 0, stream,
                       kbuf, qbuf, vtbuf, O_part, l_part);
    hipLaunchKernelGGL(combine_kernel, dim3(32, 8), dim3(256), 0, stream,
                       O_part, l_part, (const unsigned int*)x, d_out);
}